// Round 6
// baseline (316.381 us; speedup 1.0000x reference)
//
#include <hip/hip_runtime.h>

typedef _Float16 f16x4 __attribute__((ext_vector_type(4)));
typedef _Float16 f16x8 __attribute__((ext_vector_type(8)));
typedef float    f32x4 __attribute__((ext_vector_type(4)));
typedef unsigned int u32x2 __attribute__((ext_vector_type(2)));

#if __has_builtin(__builtin_amdgcn_exp2f)
#define EXP2F __builtin_amdgcn_exp2f
#else
#define EXP2F exp2f
#endif
#if __has_builtin(__builtin_amdgcn_rcpf)
#define RCPF __builtin_amdgcn_rcpf
#else
#define RCPF(x) (1.0f/(x))
#endif

#define K2 2.8853900817779268f   // 2*log2(e)

// tanh folded: tanh(y) = 1 - 2*r, r = 1/(exp2(K2*y)+1).  We propagate r and
// fold the affine (1-2r) into the next layer's weights/biases.  Inputs arrive
// pre-scaled by K2 (folded into W/b), so per activation: exp2 + add + rcp.
static __device__ __forceinline__ float sigr(float d) {
    return RCPF(EXP2F(d) + 1.0f);
}

static __device__ __forceinline__ unsigned pkrtz(float a, float b) {
    auto t = __builtin_amdgcn_cvt_pkrtz(a, b);
    return __builtin_bit_cast(unsigned, t);
}

static __device__ __forceinline__ f32x4 mfma16(f16x4 a, f16x4 b, f32x4 c) {
#if __has_builtin(__builtin_amdgcn_mfma_f32_16x16x16f16)
    return __builtin_amdgcn_mfma_f32_16x16x16f16(a, b, c, 0, 0, 0);
#else
    f16x8 a8 = {a[0], a[1], a[2], a[3], 0, 0, 0, 0};
    f16x8 b8 = {b[0], b[1], b[2], b[3], 0, 0, 0, 0};
    return __builtin_amdgcn_mfma_f32_16x16x32_f16(a8, b8, c, 0, 0, 0);
#endif
}

// ILP-2 structure: block = 256 threads = 4 waves, handles TWO 16-col batch
// tiles (A = blockIdx*32+c, B = +16).  Wave w owns hidden rows [w*16,w*16+16)
// of layers 1,2 for BOTH tiles (weights shared; two independent dep chains
// interleave -> post-barrier LDS latency and trans latency hidden in-wave).
// Grid 256 blocks = 1 block/CU, 1 wave/SIMD; 2 barriers per feval-PAIR.
// Transposed MFMA: D[m=hidden][n=batch]; lane: c = lane&15, g = lane>>4.
extern "C" __global__ __launch_bounds__(256, 1)
void rk4_kernel(const float* __restrict__ gu,  const float* __restrict__ gx0,
                const float* __restrict__ gW1, const float* __restrict__ gb1,
                const float* __restrict__ gW2, const float* __restrict__ gb2,
                const float* __restrict__ gW3, const float* __restrict__ gb3,
                const float* __restrict__ gxm, const float* __restrict__ gxs,
                const float* __restrict__ gum, const float* __restrict__ gus,
                float* __restrict__ gout)
{
    constexpr int T = 128;
    const int tid  = threadIdx.x;
    const int lane = tid & 63;
    const int w    = tid >> 6;
    const int c    = lane & 15;
    const int g    = lane >> 4;
    const int batchA = blockIdx.x * 32 + c;
    const int batchB = batchA + 16;
    const int hrow = w * 16 + g * 4;       // this lane's D rows base

    // [layer][tile][col][hidden] ; rows 72 halves = 144B stride (conflict-free b128)
    __shared__ __align__(16) _Float16 hb[2][2][16][72];

    // ---- fragments (one-time; weights L2-resident; shared by both tiles) ----
    f16x4 aW1;                     // K2*W1, real k=0..3 on g==0
#pragma unroll
    for (int j = 0; j < 4; ++j)
        aW1[j] = (_Float16)((g == 0) ? K2 * gW1[j * 64 + w * 16 + c] : 0.0f);

    f16x8 aW2[2];                  // -2*K2*W2
#pragma unroll
    for (int kt = 0; kt < 2; ++kt)
#pragma unroll
        for (int j = 0; j < 8; ++j) {
            int k = kt * 32 + g * 8 + j;
            aW2[kt][j] = (_Float16)(-2.0f * K2 * gW2[k * 64 + w * 16 + c]);
        }

    f16x8 aW3[2];                  // -2*W3, rows m=c (real c<3)
#pragma unroll
    for (int kt = 0; kt < 2; ++kt)
#pragma unroll
        for (int j = 0; j < 8; ++j) {
            int k = kt * 32 + g * 8 + j;
            aW3[kt][j] = (_Float16)((c < 3) ? -2.0f * gW3[k * 3 + c] : 0.0f);
        }

    f32x4 cb1, cb2;                // cb1 = K2*b1 ; cb2 = K2*(b2 + rowsum W2)
#pragma unroll
    for (int r = 0; r < 4; ++r) {
        int row = hrow + r;
        cb1[r] = K2 * gb1[row];
        float rs = gb2[row];
        for (int k = 0; k < 64; ++k) rs += gW2[k * 64 + row];
        cb2[r] = K2 * rs;
    }

    // L3 consts: b3 + rowsum(W3) + greybox consts (+ per-step u term, per tile).
    const float xs0 = gxs[0], xs1 = gxs[1], xs2 = gxs[2];
    const float ig0 = 1.0f / (5.0f * xs0);
    const float ig1 = 1.0f / (5.0f * xs1);
    const float ig2 = 1.0f / (5.0f * xs2);
    const float ku  = gus[0] * ig0;
    float rs3[3];
#pragma unroll
    for (int m = 0; m < 3; ++m) {
        float s = gb3[m];
        for (int k = 0; k < 64; ++k) s += gW3[k * 3 + m];
        rs3[m] = s;
    }
    const float cgb0_base = rs3[0] + (gum[0] - gxm[0]) * ig0;
    f32x4 cgbA, cgbB;
    cgbA[1] = cgbB[1] = rs3[1] - gxm[1] * ig1;
    cgbA[2] = cgbB[2] = rs3[2] - gxm[2] * ig2;
    cgbA[3] = cgbB[3] = 0.0f;

    float xA0 = gx0[batchA * 3 + 0], xA1 = gx0[batchA * 3 + 1], xA2 = gx0[batchA * 3 + 2];
    float xB0 = gx0[batchB * 3 + 0], xB1 = gx0[batchB * 3 + 1], xB2 = gx0[batchB * 3 + 2];

    // feval for both tiles, interleaved (two independent chains, shared barriers)
    auto feval2 = [&](float eA0, float eA1, float eA2, float uA,
                      float eB0, float eB1, float eB2, float uB,
                      float& oA0, float& oA1, float& oA2,
                      float& oB0, float& oB1, float& oB2) {
        unsigned zA01 = 0u, zA23 = 0u, zB01 = 0u, zB23 = 0u;
        if (g == 0) {
            zA01 = pkrtz(eA0, eA1); zA23 = pkrtz(eA2, uA);
            zB01 = pkrtz(eB0, eB1); zB23 = pkrtz(eB2, uB);
        }
        u32x2 ziA = {zA01, zA23}, ziB = {zB01, zB23};
        f16x4 zbA = __builtin_bit_cast(f16x4, ziA);
        f16x4 zbB = __builtin_bit_cast(f16x4, ziB);

        // L1 (both tiles)
        f32x4 d1A = mfma16(aW1, zbA, cb1);
        f32x4 d1B = mfma16(aW1, zbB, cb1);
        u32x2 hwA = {pkrtz(sigr(d1A[0]), sigr(d1A[1])), pkrtz(sigr(d1A[2]), sigr(d1A[3]))};
        u32x2 hwB = {pkrtz(sigr(d1B[0]), sigr(d1B[1])), pkrtz(sigr(d1B[2]), sigr(d1B[3]))};
        *(u32x2*)&hb[0][0][c][hrow] = hwA;
        *(u32x2*)&hb[0][1][c][hrow] = hwB;
        __syncthreads();
        f16x8 hA0A = *(const f16x8*)&hb[0][0][c][g * 8];
        f16x8 hA1A = *(const f16x8*)&hb[0][0][c][32 + g * 8];
        f16x8 hA0B = *(const f16x8*)&hb[0][1][c][g * 8];
        f16x8 hA1B = *(const f16x8*)&hb[0][1][c][32 + g * 8];

        // L2 (both tiles)
        f32x4 d2A = __builtin_amdgcn_mfma_f32_16x16x32_f16(aW2[0], hA0A, cb2, 0, 0, 0);
        f32x4 d2B = __builtin_amdgcn_mfma_f32_16x16x32_f16(aW2[0], hA0B, cb2, 0, 0, 0);
        d2A = __builtin_amdgcn_mfma_f32_16x16x32_f16(aW2[1], hA1A, d2A, 0, 0, 0);
        d2B = __builtin_amdgcn_mfma_f32_16x16x32_f16(aW2[1], hA1B, d2B, 0, 0, 0);
        u32x2 qwA = {pkrtz(sigr(d2A[0]), sigr(d2A[1])), pkrtz(sigr(d2A[2]), sigr(d2A[3]))};
        u32x2 qwB = {pkrtz(sigr(d2B[0]), sigr(d2B[1])), pkrtz(sigr(d2B[2]), sigr(d2B[3]))};
        *(u32x2*)&hb[1][0][c][hrow] = qwA;
        *(u32x2*)&hb[1][1][c][hrow] = qwB;
        __syncthreads();
        f16x8 hB0A = *(const f16x8*)&hb[1][0][c][g * 8];
        f16x8 hB1A = *(const f16x8*)&hb[1][0][c][32 + g * 8];
        f16x8 hB0B = *(const f16x8*)&hb[1][1][c][g * 8];
        f16x8 hB1B = *(const f16x8*)&hb[1][1][c][32 + g * 8];

        // L3 (both tiles)
        f32x4 d3A = __builtin_amdgcn_mfma_f32_16x16x32_f16(aW3[0], hB0A, cgbA, 0, 0, 0);
        f32x4 d3B = __builtin_amdgcn_mfma_f32_16x16x32_f16(aW3[0], hB0B, cgbB, 0, 0, 0);
        d3A = __builtin_amdgcn_mfma_f32_16x16x32_f16(aW3[1], hB1A, d3A, 0, 0, 0);
        d3B = __builtin_amdgcn_mfma_f32_16x16x32_f16(aW3[1], hB1B, d3B, 0, 0, 0);

        // greybox residual: -e/TAU (xstd cancels exactly)
        oA0 = __builtin_fmaf(-0.2f, eA0, d3A[0]);
        oA1 = __builtin_fmaf(-0.2f, eA1, d3A[1]);
        oA2 = __builtin_fmaf(-0.2f, eA2, d3A[2]);
        oB0 = __builtin_fmaf(-0.2f, eB0, d3B[0]);
        oB1 = __builtin_fmaf(-0.2f, eB1, d3B[1]);
        oB2 = __builtin_fmaf(-0.2f, eB2, d3B[2]);
    };

    float uA = gu[batchA * T];
    float uB = gu[batchB * T];
    float* orowA = gout + (size_t)batchA * (3 * T);
    float* orowB = gout + (size_t)batchB * (3 * T);

    for (int t = 0; t < T; ++t) {
        if (w == 0 && g == 0) {          // ys[t] = pre-step state
            orowA[t * 3 + 0] = xA0; orowA[t * 3 + 1] = xA1; orowA[t * 3 + 2] = xA2;
            orowB[t * 3 + 0] = xB0; orowB[t * 3 + 1] = xB1; orowB[t * 3 + 2] = xB2;
        }
        int tn = (t + 1 < T) ? t + 1 : t;
        float unA = gu[batchA * T + tn];
        float unB = gu[batchB * T + tn];

        cgbA[0] = __builtin_fmaf(uA, ku, cgb0_base);
        cgbB[0] = __builtin_fmaf(uB, ku, cgb0_base);

        float aA0, aA1, aA2, bA0, bA1, bA2, cA0, cA1, cA2, dA0, dA1, dA2;
        float aB0, aB1, aB2, bB0, bB1, bB2, cB0, cB1, cB2, dB0, dB1, dB2;

        feval2(xA0, xA1, xA2, uA,  xB0, xB1, xB2, uB,
               aA0, aA1, aA2, aB0, aB1, aB2);
        feval2(xA0 + 0.5f * aA0, xA1 + 0.5f * aA1, xA2 + 0.5f * aA2, uA,
               xB0 + 0.5f * aB0, xB1 + 0.5f * aB1, xB2 + 0.5f * aB2, uB,
               bA0, bA1, bA2, bB0, bB1, bB2);
        feval2(xA0 + 0.5f * bA0, xA1 + 0.5f * bA1, xA2 + 0.5f * bA2, uA,
               xB0 + 0.5f * bB0, xB1 + 0.5f * bB1, xB2 + 0.5f * bB2, uB,
               cA0, cA1, cA2, cB0, cB1, cB2);
        feval2(xA0 + cA0, xA1 + cA1, xA2 + cA2, uA,
               xB0 + cB0, xB1 + cB1, xB2 + cB2, uB,
               dA0, dA1, dA2, dB0, dB1, dB2);

        xA0 += (1.0f / 6.0f) * (aA0 + 2.0f * bA0 + 2.0f * cA0 + dA0);
        xA1 += (1.0f / 6.0f) * (aA1 + 2.0f * bA1 + 2.0f * cA1 + dA1);
        xA2 += (1.0f / 6.0f) * (aA2 + 2.0f * bA2 + 2.0f * cA2 + dA2);
        xB0 += (1.0f / 6.0f) * (aB0 + 2.0f * bB0 + 2.0f * cB0 + dB0);
        xB1 += (1.0f / 6.0f) * (aB1 + 2.0f * bB1 + 2.0f * cB1 + dB1);
        xB2 += (1.0f / 6.0f) * (aB2 + 2.0f * bB2 + 2.0f * cB2 + dB2);
        uA = unA;
        uB = unB;
    }
}

extern "C" void kernel_launch(void* const* d_in, const int* in_sizes, int n_in,
                              void* d_out, int out_size, void* d_ws, size_t ws_size,
                              hipStream_t stream) {
    const float* u  = (const float*)d_in[0];
    const float* x0 = (const float*)d_in[1];
    const float* W1 = (const float*)d_in[2];
    const float* b1 = (const float*)d_in[3];
    const float* W2 = (const float*)d_in[4];
    const float* b2 = (const float*)d_in[5];
    const float* W3 = (const float*)d_in[6];
    const float* b3 = (const float*)d_in[7];
    const float* xm = (const float*)d_in[8];
    const float* xs = (const float*)d_in[9];
    const float* um = (const float*)d_in[10];
    const float* us = (const float*)d_in[11];
    // 8192 / 32 cols per block = 256 blocks x 256 threads (ILP-2 tiles/block)
    rk4_kernel<<<256, 256, 0, stream>>>(u, x0, W1, b1, W2, b2, W3, b3,
                                        xm, xs, um, us, (float*)d_out);
}

// Round 7
// 315.608 us; speedup vs baseline: 1.0024x; 1.0024x over previous
//
#include <hip/hip_runtime.h>

typedef _Float16 f16x4 __attribute__((ext_vector_type(4)));
typedef _Float16 f16x8 __attribute__((ext_vector_type(8)));
typedef float    f32x4 __attribute__((ext_vector_type(4)));
typedef unsigned int u32x2 __attribute__((ext_vector_type(2)));

#if __has_builtin(__builtin_amdgcn_exp2f)
#define EXP2F __builtin_amdgcn_exp2f
#else
#define EXP2F exp2f
#endif
#if __has_builtin(__builtin_amdgcn_rcpf)
#define RCPF __builtin_amdgcn_rcpf
#else
#define RCPF(x) (1.0f/(x))
#endif

#define K2 2.8853900817779268f   // 2*log2(e)

// tanh folded: tanh(y) = 1 - 2*r, r = 1/(exp2(K2*y)+1).  We propagate r and
// fold the affine (1-2r) into the next layer's weights/biases.
static __device__ __forceinline__ float sigr(float d) {
    return RCPF(EXP2F(d) + 1.0f);
}

static __device__ __forceinline__ unsigned pkrtz(float a, float b) {
    auto t = __builtin_amdgcn_cvt_pkrtz(a, b);
    return __builtin_bit_cast(unsigned, t);
}

// Logical MFMA contraction: D[m][n] += sum_{g,j} A[(m,g),j] * B[(n,g),j].
// Native 16x16x16 uses k=g*4+j; the x32 fallback relabels k=g*8+j with zero
// pads on BOTH operands -> identical sum.  Crucially D's row map (g*4+reg)
// equals B's (g,j) map, so an activated D-frag feeds the next layer's B
// directly (k-slice = its M-tile index) with NO cross-lane movement.
static __device__ __forceinline__ f32x4 mfma16(f16x4 a, f16x4 b, f32x4 c) {
#if __has_builtin(__builtin_amdgcn_mfma_f32_16x16x16f16)
    return __builtin_amdgcn_mfma_f32_16x16x16f16(a, b, c, 0, 0, 0);
#else
    f16x8 a8 = {a[0], a[1], a[2], a[3], 0, 0, 0, 0};
    f16x8 b8 = {b[0], b[1], b[2], b[3], 0, 0, 0, 0};
    return __builtin_amdgcn_mfma_f32_16x16x32_f16(a8, b8, c, 0, 0, 0);
#endif
}

// Barrier-free fat-wave: ONE wave owns 16 batch columns and the ENTIRE net.
// No LDS, no __syncthreads, pure in-register dataflow:
//   L1: 4 MFMAs (M-tiles 0..3)        -> d1[mt]   (all values real)
//   act+pack                          -> pk1[mt]  (f16x4 per lane)
//   L2: 4 M-tiles x 4 K-slices, slice ks consumes pk1[ks]  (16 MFMAs)
//   act+pack                          -> pk2[ks]
//   L3: 4 K-slices (rows 0..2 real)   -> d3, output on g==0 lanes regs 0..2
// lane: c = lane&15 (batch col), g = lane>>4.  State lives on g==0 lanes.
extern "C" __global__ __launch_bounds__(64, 1)
void rk4_kernel(const float* __restrict__ gu,  const float* __restrict__ gx0,
                const float* __restrict__ gW1, const float* __restrict__ gb1,
                const float* __restrict__ gW2, const float* __restrict__ gb2,
                const float* __restrict__ gW3, const float* __restrict__ gb3,
                const float* __restrict__ gxm, const float* __restrict__ gxs,
                const float* __restrict__ gum, const float* __restrict__ gus,
                float* __restrict__ gout)
{
    constexpr int T = 128;
    const int lane = threadIdx.x & 63;
    const int c    = lane & 15;
    const int g    = lane >> 4;
    const int batch = blockIdx.x * 16 + c;

    // ---- fragments (one-time; weights L2-resident, broadcast loads) ----
    f16x4 aW1[4];                       // K2*W1 ; kin = g*4+j, real kin<4 (g==0)
#pragma unroll
    for (int mt = 0; mt < 4; ++mt)
#pragma unroll
        for (int j = 0; j < 4; ++j)
            aW1[mt][j] = (_Float16)((g == 0) ? K2 * gW1[j * 64 + mt * 16 + c] : 0.0f);

    f16x4 aW2[4][4];                    // -2*K2*W2 ; [M-tile mt][K-slice ks]
#pragma unroll
    for (int mt = 0; mt < 4; ++mt)
#pragma unroll
        for (int ks = 0; ks < 4; ++ks)
#pragma unroll
            for (int j = 0; j < 4; ++j)
                aW2[mt][ks][j] =
                    (_Float16)(-2.0f * K2 * gW2[(ks * 16 + g * 4 + j) * 64 + mt * 16 + c]);

    f16x4 aW3[4];                       // -2*W3 ; rows m=c (real c<3)
#pragma unroll
    for (int ks = 0; ks < 4; ++ks)
#pragma unroll
        for (int j = 0; j < 4; ++j)
            aW3[ks][j] =
                (_Float16)((c < 3) ? -2.0f * gW3[(ks * 16 + g * 4 + j) * 3 + c] : 0.0f);

    f32x4 cb1[4], cb2[4];               // cb1 = K2*b1 ; cb2 = K2*(b2 + rowsum W2)
#pragma unroll
    for (int mt = 0; mt < 4; ++mt)
#pragma unroll
        for (int r = 0; r < 4; ++r) {
            int row = mt * 16 + g * 4 + r;
            cb1[mt][r] = K2 * gb1[row];
            float rs = gb2[row];
            for (int k = 0; k < 64; ++k) rs += gW2[k * 64 + row];
            cb2[mt][r] = K2 * rs;
        }

    // L3 consts: b3 + rowsum(W3) + greybox consts (+ per-step u term).
    const float xs0 = gxs[0], xs1 = gxs[1], xs2 = gxs[2];
    const float ig0 = 1.0f / (5.0f * xs0);
    const float ig1 = 1.0f / (5.0f * xs1);
    const float ig2 = 1.0f / (5.0f * xs2);
    const float ku  = gus[0] * ig0;
    float rs3[3];
#pragma unroll
    for (int m = 0; m < 3; ++m) {
        float s = gb3[m];
        for (int k = 0; k < 64; ++k) s += gW3[k * 3 + m];
        rs3[m] = s;
    }
    const float cgb0_base = rs3[0] + (gum[0] - gxm[0]) * ig0;
    f32x4 cgb;                          // valid on g==0, regs 0..2
    cgb[1] = (g == 0) ? (rs3[1] - gxm[1] * ig1) : 0.0f;
    cgb[2] = (g == 0) ? (rs3[2] - gxm[2] * ig2) : 0.0f;
    cgb[3] = 0.0f;

    float x0v = gx0[batch * 3 + 0];
    float x1v = gx0[batch * 3 + 1];
    float x2v = gx0[batch * 3 + 2];

    auto feval = [&](float e0, float e1, float e2, float ue,
                     float& o0, float& o1, float& o2) {
        // z B-frag: kin=0..3 -> (x0,x1,x2,u) on g==0 lanes.
        unsigned z01 = 0u, z23 = 0u;
        if (g == 0) { z01 = pkrtz(e0, e1); z23 = pkrtz(e2, ue); }
        u32x2 zi = {z01, z23};
        f16x4 zb = __builtin_bit_cast(f16x4, zi);

        // L1: 4 M-tiles
        f32x4 d1_0 = mfma16(aW1[0], zb, cb1[0]);
        f32x4 d1_1 = mfma16(aW1[1], zb, cb1[1]);
        f32x4 d1_2 = mfma16(aW1[2], zb, cb1[2]);
        f32x4 d1_3 = mfma16(aW1[3], zb, cb1[3]);

        // act+pack: pk1[ks] is both "H1 tile ks" and L2's K-slice-ks B-frag
        f16x4 pk1[4];
        {
            u32x2 t0 = {pkrtz(sigr(d1_0[0]), sigr(d1_0[1])), pkrtz(sigr(d1_0[2]), sigr(d1_0[3]))};
            u32x2 t1 = {pkrtz(sigr(d1_1[0]), sigr(d1_1[1])), pkrtz(sigr(d1_1[2]), sigr(d1_1[3]))};
            u32x2 t2 = {pkrtz(sigr(d1_2[0]), sigr(d1_2[1])), pkrtz(sigr(d1_2[2]), sigr(d1_2[3]))};
            u32x2 t3 = {pkrtz(sigr(d1_3[0]), sigr(d1_3[1])), pkrtz(sigr(d1_3[2]), sigr(d1_3[3]))};
            pk1[0] = __builtin_bit_cast(f16x4, t0);
            pk1[1] = __builtin_bit_cast(f16x4, t1);
            pk1[2] = __builtin_bit_cast(f16x4, t2);
            pk1[3] = __builtin_bit_cast(f16x4, t3);
        }

        // L2: 4 M-tiles x 4 K-slices (chained accumulators, 4 independent chains)
        f32x4 d2_0 = mfma16(aW2[0][0], pk1[0], cb2[0]);
        f32x4 d2_1 = mfma16(aW2[1][0], pk1[0], cb2[1]);
        f32x4 d2_2 = mfma16(aW2[2][0], pk1[0], cb2[2]);
        f32x4 d2_3 = mfma16(aW2[3][0], pk1[0], cb2[3]);
#pragma unroll
        for (int ks = 1; ks < 4; ++ks) {
            d2_0 = mfma16(aW2[0][ks], pk1[ks], d2_0);
            d2_1 = mfma16(aW2[1][ks], pk1[ks], d2_1);
            d2_2 = mfma16(aW2[2][ks], pk1[ks], d2_2);
            d2_3 = mfma16(aW2[3][ks], pk1[ks], d2_3);
        }

        f16x4 pk2[4];
        {
            u32x2 t0 = {pkrtz(sigr(d2_0[0]), sigr(d2_0[1])), pkrtz(sigr(d2_0[2]), sigr(d2_0[3]))};
            u32x2 t1 = {pkrtz(sigr(d2_1[0]), sigr(d2_1[1])), pkrtz(sigr(d2_1[2]), sigr(d2_1[3]))};
            u32x2 t2 = {pkrtz(sigr(d2_2[0]), sigr(d2_2[1])), pkrtz(sigr(d2_2[2]), sigr(d2_2[3]))};
            u32x2 t3 = {pkrtz(sigr(d2_3[0]), sigr(d2_3[1])), pkrtz(sigr(d2_3[2]), sigr(d2_3[3]))};
            pk2[0] = __builtin_bit_cast(f16x4, t0);
            pk2[1] = __builtin_bit_cast(f16x4, t1);
            pk2[2] = __builtin_bit_cast(f16x4, t2);
            pk2[3] = __builtin_bit_cast(f16x4, t3);
        }

        // L3: 4 K-slices; rows 0..2 land on g==0 lanes regs 0..2
        f32x4 d3 = mfma16(aW3[0], pk2[0], cgb);
        d3 = mfma16(aW3[1], pk2[1], d3);
        d3 = mfma16(aW3[2], pk2[2], d3);
        d3 = mfma16(aW3[3], pk2[3], d3);

        // greybox residual: -e/TAU (xstd cancels exactly)
        o0 = __builtin_fmaf(-0.2f, e0, d3[0]);
        o1 = __builtin_fmaf(-0.2f, e1, d3[1]);
        o2 = __builtin_fmaf(-0.2f, e2, d3[2]);
    };

    float ucur = gu[batch * T];
    float* orow = gout + (size_t)batch * (3 * T);

    for (int t = 0; t < T; ++t) {
        if (g == 0) {                    // ys[t] = pre-step state
            orow[t * 3 + 0] = x0v;
            orow[t * 3 + 1] = x1v;
            orow[t * 3 + 2] = x2v;
        }
        float unext = gu[batch * T + ((t + 1 < T) ? t + 1 : t)];

        cgb[0] = (g == 0) ? __builtin_fmaf(ucur, ku, cgb0_base) : 0.0f;

        float a0, a1, a2, b0, b1v, b2v, c0, c1, c2, d0, d1v, d2v;
        feval(x0v, x1v, x2v, ucur, a0, a1, a2);
        feval(x0v + 0.5f * a0, x1v + 0.5f * a1, x2v + 0.5f * a2, ucur, b0, b1v, b2v);
        feval(x0v + 0.5f * b0, x1v + 0.5f * b1v, x2v + 0.5f * b2v, ucur, c0, c1, c2);
        feval(x0v + c0, x1v + c1, x2v + c2, ucur, d0, d1v, d2v);

        x0v += (1.0f / 6.0f) * (a0 + 2.0f * b0 + 2.0f * c0 + d0);
        x1v += (1.0f / 6.0f) * (a1 + 2.0f * b1v + 2.0f * c1 + d1v);
        x2v += (1.0f / 6.0f) * (a2 + 2.0f * b2v + 2.0f * c2 + d2v);
        ucur = unext;
    }
}

extern "C" void kernel_launch(void* const* d_in, const int* in_sizes, int n_in,
                              void* d_out, int out_size, void* d_ws, size_t ws_size,
                              hipStream_t stream) {
    const float* u  = (const float*)d_in[0];
    const float* x0 = (const float*)d_in[1];
    const float* W1 = (const float*)d_in[2];
    const float* b1 = (const float*)d_in[3];
    const float* W2 = (const float*)d_in[4];
    const float* b2 = (const float*)d_in[5];
    const float* W3 = (const float*)d_in[6];
    const float* b3 = (const float*)d_in[7];
    const float* xm = (const float*)d_in[8];
    const float* xs = (const float*)d_in[9];
    const float* um = (const float*)d_in[10];
    const float* us = (const float*)d_in[11];
    // 8192 / 16 cols per wave = 512 independent 64-thread blocks (no barriers)
    rk4_kernel<<<512, 64, 0, stream>>>(u, x0, W1, b1, W2, b2, W3, b3,
                                       xm, xs, um, us, (float*)d_out);
}

// Round 8
// 292.496 us; speedup vs baseline: 1.0817x; 1.0790x over previous
//
#include <hip/hip_runtime.h>

typedef _Float16 f16x4 __attribute__((ext_vector_type(4)));
typedef _Float16 f16x8 __attribute__((ext_vector_type(8)));
typedef float    f32x4 __attribute__((ext_vector_type(4)));
typedef unsigned int u32x2 __attribute__((ext_vector_type(2)));

#if __has_builtin(__builtin_amdgcn_exp2f)
#define EXP2F __builtin_amdgcn_exp2f
#else
#define EXP2F exp2f
#endif
#if __has_builtin(__builtin_amdgcn_rcpf)
#define RCPF __builtin_amdgcn_rcpf
#else
#define RCPF(x) (1.0f/(x))
#endif

#define K2 2.8853900817779268f   // 2*log2(e)

// tanh folded: tanh(y) = 1 - 2*r, r = 1/(exp2(K2*y)+1).  We propagate r and
// fold the affine (1-2r) into the next layer's weights/biases.
static __device__ __forceinline__ float sigr(float d) {
    return RCPF(EXP2F(d) + 1.0f);
}

static __device__ __forceinline__ unsigned pkrtz(float a, float b) {
    auto t = __builtin_amdgcn_cvt_pkrtz(a, b);
    return __builtin_bit_cast(unsigned, t);
}

static __device__ __forceinline__ f32x4 mfma16(f16x4 a, f16x4 b, f32x4 c) {
#if __has_builtin(__builtin_amdgcn_mfma_f32_16x16x16f16)
    return __builtin_amdgcn_mfma_f32_16x16x16f16(a, b, c, 0, 0, 0);
#else
    f16x8 a8 = {a[0], a[1], a[2], a[3], 0, 0, 0, 0};
    f16x8 b8 = {b[0], b[1], b[2], b[3], 0, 0, 0, 0};
    return __builtin_amdgcn_mfma_f32_16x16x32_f16(a8, b8, c, 0, 0, 0);
#endif
}

// Barrier WITHOUT vmcnt drain: only LDS ordering is needed across waves
// (gout stores / u loads are wave-private).  "memory" clobber pins source
// ordering of the surrounding ds ops.
static __device__ __forceinline__ void barrier_lds() {
    asm volatile("s_waitcnt lgkmcnt(0)\n\ts_barrier" ::: "memory");
}

template<int N> struct ic { static constexpr int v = N; };

// Skewed dual-tile: block = 512 threads = 8 waves = 2 tiles x 4 hidden slices.
// Tile A = waves 0..3, tile B = waves 4..7 (wt = wv>>2, slice ws = wv&3).
// B runs one region behind A: every barrier region has 4 waves doing the
// heavy [S2(L3)+bookkeeping+S0(L1)] chunk and 4 doing the light [S1(L2)]
// chunk -> each SIMD's two resident waves always hold independent,
// heterogeneous chains (deterministic anti-phase; R5 relied on scheduler
// luck, R6's lockstep broke it).  2 barriers per tile-feval, same as R5.
// Single-buffer LDS per tile/layer is hazard-free: each buffer is written
// in one region and read in the next (one barrier apart).
extern "C" __global__ __launch_bounds__(512, 2)
void rk4_kernel(const float* __restrict__ gu,  const float* __restrict__ gx0,
                const float* __restrict__ gW1, const float* __restrict__ gb1,
                const float* __restrict__ gW2, const float* __restrict__ gb2,
                const float* __restrict__ gW3, const float* __restrict__ gb3,
                const float* __restrict__ gxm, const float* __restrict__ gxs,
                const float* __restrict__ gum, const float* __restrict__ gus,
                float* __restrict__ gout)
{
    constexpr int T = 128;
    const int tid  = threadIdx.x;
    const int lane = tid & 63;
    const int wv   = tid >> 6;      // 0..7
    const int wt   = wv >> 2;       // tile role: 0 = A, 1 = B
    const int ws   = wv & 3;        // hidden slice
    const int c    = lane & 15;
    const int g    = lane >> 4;
    const int batch = blockIdx.x * 32 + wt * 16 + c;
    const int hrow  = ws * 16 + g * 4;

    // rows 72 halves = 144B stride -> conflict-free b128 reads.
    __shared__ __align__(16) _Float16 h1[2][16][72];
    __shared__ __align__(16) _Float16 h2[2][16][72];

    // ---- weight fragments (one-time; L2-resident) ----
    f16x4 aW1;                      // K2*W1, real k=0..3 on g==0
#pragma unroll
    for (int j = 0; j < 4; ++j)
        aW1[j] = (_Float16)((g == 0) ? K2 * gW1[j * 64 + ws * 16 + c] : 0.0f);

    f16x8 aW2[2];                   // -2*K2*W2
#pragma unroll
    for (int kt = 0; kt < 2; ++kt)
#pragma unroll
        for (int j = 0; j < 8; ++j) {
            int k = kt * 32 + g * 8 + j;
            aW2[kt][j] = (_Float16)(-2.0f * K2 * gW2[k * 64 + ws * 16 + c]);
        }

    f16x8 aW3[2];                   // -2*W3, rows m=c (real c<3)
#pragma unroll
    for (int kt = 0; kt < 2; ++kt)
#pragma unroll
        for (int j = 0; j < 8; ++j) {
            int k = kt * 32 + g * 8 + j;
            aW3[kt][j] = (_Float16)((c < 3) ? -2.0f * gW3[k * 3 + c] : 0.0f);
        }

    f32x4 cb1, cb2;                 // cb1 = K2*b1 ; cb2 = K2*(b2 + rowsum W2)
#pragma unroll
    for (int r = 0; r < 4; ++r) {
        int row = hrow + r;
        cb1[r] = K2 * gb1[row];
        float rs = gb2[row];
        for (int k = 0; k < 64; ++k) rs += gW2[k * 64 + row];
        cb2[r] = K2 * rs;
    }

    // L3 consts: b3 + rowsum(W3) + greybox consts (+ per-step u term).
    const float xs0 = gxs[0], xs1 = gxs[1], xs2 = gxs[2];
    const float ig0 = 1.0f / (5.0f * xs0);
    const float ig1 = 1.0f / (5.0f * xs1);
    const float ig2 = 1.0f / (5.0f * xs2);
    const float ku  = gus[0] * ig0;
    float rs3[3];
#pragma unroll
    for (int m = 0; m < 3; ++m) {
        float s = gb3[m];
        for (int k = 0; k < 64; ++k) s += gW3[k * 3 + m];
        rs3[m] = s;
    }
    const float cgb0_base = rs3[0] + (gum[0] - gxm[0]) * ig0;
    f32x4 cgb;
    cgb[1] = rs3[1] - gxm[1] * ig1;
    cgb[2] = rs3[2] - gxm[2] * ig2;
    cgb[3] = 0.0f;

    // ---- per-tile serial state (each wave holds its tile's full copy) ----
    float x0v = gx0[batch * 3 + 0];
    float x1v = gx0[batch * 3 + 1];
    float x2v = gx0[batch * 3 + 2];
    float e0 = x0v, e1 = x1v, e2 = x2v;    // stage input
    float ks0 = 0.0f, ks1 = 0.0f, ks2 = 0.0f;
    float u  = gu[batch * T];
    float un = u;
    cgb[0] = __builtin_fmaf(u, ku, cgb0_base);
    int t = 0;
    float* orow = gout + (size_t)batch * (3 * T);

    // S0: z-pack + L1 + act -> write h1[wt]
    auto S0 = [&]() {
        unsigned z01 = 0u, z23 = 0u;
        if (g == 0) { z01 = pkrtz(e0, e1); z23 = pkrtz(e2, u); }
        u32x2 zi = {z01, z23};
        f16x4 zb = __builtin_bit_cast(f16x4, zi);
        f32x4 d1 = mfma16(aW1, zb, cb1);
        u32x2 hw = {pkrtz(sigr(d1[0]), sigr(d1[1])),
                    pkrtz(sigr(d1[2]), sigr(d1[3]))};
        *(u32x2*)&h1[wt][c][hrow] = hw;
    };
    // S1: read h1[wt] -> L2 + act -> write h2[wt]
    auto S1 = [&]() {
        f16x8 a0 = *(const f16x8*)&h1[wt][c][g * 8];
        f16x8 a1 = *(const f16x8*)&h1[wt][c][32 + g * 8];
        f32x4 d2 = __builtin_amdgcn_mfma_f32_16x16x32_f16(aW2[0], a0, cb2, 0, 0, 0);
        d2 = __builtin_amdgcn_mfma_f32_16x16x32_f16(aW2[1], a1, d2, 0, 0, 0);
        u32x2 qw = {pkrtz(sigr(d2[0]), sigr(d2[1])),
                    pkrtz(sigr(d2[2]), sigr(d2[3]))};
        *(u32x2*)&h2[wt][c][hrow] = qw;
    };
    // S2<ST>: read h2[wt] -> L3 -> k; RK4 stage bookkeeping (compile-time ST)
    auto S2 = [&](auto stc) {
        constexpr int ST = decltype(stc)::v;
        f16x8 b0 = *(const f16x8*)&h2[wt][c][g * 8];
        f16x8 b1 = *(const f16x8*)&h2[wt][c][32 + g * 8];
        f32x4 d3 = __builtin_amdgcn_mfma_f32_16x16x32_f16(aW3[0], b0, cgb, 0, 0, 0);
        d3 = __builtin_amdgcn_mfma_f32_16x16x32_f16(aW3[1], b1, d3, 0, 0, 0);
        float o0 = __builtin_fmaf(-0.2f, e0, d3[0]);
        float o1 = __builtin_fmaf(-0.2f, e1, d3[1]);
        float o2 = __builtin_fmaf(-0.2f, e2, d3[2]);
        if constexpr (ST == 0) {
            ks0 = o0; ks1 = o1; ks2 = o2;
            e0 = __builtin_fmaf(0.5f, o0, x0v);
            e1 = __builtin_fmaf(0.5f, o1, x1v);
            e2 = __builtin_fmaf(0.5f, o2, x2v);
            un = gu[batch * T + ((t + 1 < T) ? t + 1 : T - 1)];   // prefetch
        } else if constexpr (ST == 1) {
            ks0 = __builtin_fmaf(2.0f, o0, ks0);
            ks1 = __builtin_fmaf(2.0f, o1, ks1);
            ks2 = __builtin_fmaf(2.0f, o2, ks2);
            e0 = __builtin_fmaf(0.5f, o0, x0v);
            e1 = __builtin_fmaf(0.5f, o1, x1v);
            e2 = __builtin_fmaf(0.5f, o2, x2v);
        } else if constexpr (ST == 2) {
            ks0 = __builtin_fmaf(2.0f, o0, ks0);
            ks1 = __builtin_fmaf(2.0f, o1, ks1);
            ks2 = __builtin_fmaf(2.0f, o2, ks2);
            e0 = x0v + o0;
            e1 = x1v + o1;
            e2 = x2v + o2;
        } else {
            x0v += (1.0f / 6.0f) * (ks0 + o0);
            x1v += (1.0f / 6.0f) * (ks1 + o1);
            x2v += (1.0f / 6.0f) * (ks2 + o2);
            int tn = t + 1;
            if (tn < T && ws == 0 && g == 0) {    // ys[tn] = new state
                orow[tn * 3 + 0] = x0v;
                orow[tn * 3 + 1] = x1v;
                orow[tn * 3 + 2] = x2v;
            }
            t = tn;
            u = un;
            cgb[0] = __builtin_fmaf(u, ku, cgb0_base);
            e0 = x0v; e1 = x1v; e2 = x2v;
        }
    };

    // ---- prologue ----
    if (ws == 0 && g == 0) {                      // ys[0] for this tile
        orow[0] = x0v; orow[1] = x1v; orow[2] = x2v;
    }
    if (wt == 0) { S0(); }                        // A.S0(f=0)
    barrier_lds();
    if (wt == 0) { S1(); } else { S0(); }         // A.S1(0) | B.S0(0)
    barrier_lds();

    // ---- steady state: 511 feval-pairs (A at f, B at f, B one region late) ----
#define PAIR(S)                                                   \
    if (wt == 0) { S2(ic<S>{}); S0(); } else { S1(); }            \
    barrier_lds();                                                \
    if (wt == 0) { S1(); } else { S2(ic<S>{}); S0(); }            \
    barrier_lds();

#pragma unroll 1
    for (int it = 0; it < 127; ++it) {
        PAIR(0) PAIR(1) PAIR(2) PAIR(3)
    }
    PAIR(0) PAIR(1) PAIR(2)                       // f = 508..510 (step 127 st 0..2)

    // ---- final feval f = 511 (stage 3; no S0(512)/S1(512)) ----
    if (wt == 0) { S2(ic<3>{}); } else { S1(); }
    barrier_lds();
    if (wt == 1) { S2(ic<3>{}); }
#undef PAIR
}

extern "C" void kernel_launch(void* const* d_in, const int* in_sizes, int n_in,
                              void* d_out, int out_size, void* d_ws, size_t ws_size,
                              hipStream_t stream) {
    const float* u  = (const float*)d_in[0];
    const float* x0 = (const float*)d_in[1];
    const float* W1 = (const float*)d_in[2];
    const float* b1 = (const float*)d_in[3];
    const float* W2 = (const float*)d_in[4];
    const float* b2 = (const float*)d_in[5];
    const float* W3 = (const float*)d_in[6];
    const float* b3 = (const float*)d_in[7];
    const float* xm = (const float*)d_in[8];
    const float* xs = (const float*)d_in[9];
    const float* um = (const float*)d_in[10];
    const float* us = (const float*)d_in[11];
    // 8192 / 32 cols per block = 256 blocks x 512 threads (2 tiles x 4 slices)
    rk4_kernel<<<256, 512, 0, stream>>>(u, x0, W1, b1, W2, b2, W3, b3,
                                        xm, xs, um, us, (float*)d_out);
}

// Round 9
// 221.020 us; speedup vs baseline: 1.4315x; 1.3234x over previous
//
#include <hip/hip_runtime.h>

typedef _Float16 f16x4 __attribute__((ext_vector_type(4)));
typedef _Float16 f16x8 __attribute__((ext_vector_type(8)));
typedef float    f32x4 __attribute__((ext_vector_type(4)));
typedef unsigned int u32x2 __attribute__((ext_vector_type(2)));

#if __has_builtin(__builtin_amdgcn_exp2f)
#define EXP2F __builtin_amdgcn_exp2f
#else
#define EXP2F exp2f
#endif
#if __has_builtin(__builtin_amdgcn_rcpf)
#define RCPF __builtin_amdgcn_rcpf
#else
#define RCPF(x) (1.0f/(x))
#endif

#define K2 2.8853900817779268f   // 2*log2(e)

// tanh folded: tanh(y) = 1 - 2*r, r = 1/(exp2(K2*y)+1).  We propagate r and
// fold the affine (1-2r) into the next layer's weights/biases.  Inputs arrive
// pre-scaled by K2 (folded into W/b), so per activation: exp2 + add + rcp.
static __device__ __forceinline__ float sigr(float d) {
    return RCPF(EXP2F(d) + 1.0f);
}

static __device__ __forceinline__ unsigned pkrtz(float a, float b) {
    auto t = __builtin_amdgcn_cvt_pkrtz(a, b);
    return __builtin_bit_cast(unsigned, t);
}

static __device__ __forceinline__ f32x4 mfma16(f16x4 a, f16x4 b, f32x4 c) {
#if __has_builtin(__builtin_amdgcn_mfma_f32_16x16x16f16)
    return __builtin_amdgcn_mfma_f32_16x16x16f16(a, b, c, 0, 0, 0);
#else
    f16x8 a8 = {a[0], a[1], a[2], a[3], 0, 0, 0, 0};
    f16x8 b8 = {b[0], b[1], b[2], b[3], 0, 0, 0, 0};
    return __builtin_amdgcn_mfma_f32_16x16x32_f16(a8, b8, c, 0, 0, 0);
#endif
}

// Barrier WITHOUT vmcnt drain.  Cross-wave communication in this kernel is
// exclusively via LDS (h buffers); gout stores and u loads are wave-private,
// so draining them at every barrier (__syncthreads' vmcnt(0)) only puts
// HBM store/load latency on the critical path.  lgkmcnt(0) orders the DS
// writes before s_barrier; "memory" clobber pins compiler ordering.
// (Validated in R8: passed with identical absmax.)
static __device__ __forceinline__ void barrier_lds() {
    asm volatile("s_waitcnt lgkmcnt(0)\n\ts_barrier" ::: "memory");
}

// R5 structure (best known: 225 us) + lgkm-only barriers.
// Block = 256 threads = 4 waves, 16 batch columns; wave w owns hidden rows
// [w*16, w*16+16) of layers 1,2.  Transposed MFMA: D[m=hidden][n=batch].
// lane: c = lane&15 (batch col), g = lane>>4.
// A-frag row = lane&15, k = g*KW+j.  B-frag col = lane&15, k = g*KW+j.
// C/D-frag col = lane&15, row = g*4+reg.
// 512 blocks -> 2 independent blocks/CU whose free phase drift fills each
// other's post-barrier LDS/MFMA latency (R6/R7/R8 proved every alternative
// -- lockstep dual-tile, no-TLP fat wave, single-barrier skew -- is worse).
extern "C" __global__ __launch_bounds__(256, 2)
void rk4_kernel(const float* __restrict__ gu,  const float* __restrict__ gx0,
                const float* __restrict__ gW1, const float* __restrict__ gb1,
                const float* __restrict__ gW2, const float* __restrict__ gb2,
                const float* __restrict__ gW3, const float* __restrict__ gb3,
                const float* __restrict__ gxm, const float* __restrict__ gxs,
                const float* __restrict__ gum, const float* __restrict__ gus,
                float* __restrict__ gout)
{
    constexpr int T = 128;
    const int tid  = threadIdx.x;
    const int lane = tid & 63;
    const int w    = tid >> 6;
    const int c    = lane & 15;
    const int g    = lane >> 4;
    const int batch = blockIdx.x * 16 + c;

    // rows 72 halves = 144B stride -> conflict-free b128 reads.
    __shared__ __align__(16) _Float16 hb[2][16][72];

    // ---- fragments (one-time; weights L2-resident) ----
    // L1 A (16x16x16): K2*W1, real k=0..3 on g==0.
    f16x4 aW1;
#pragma unroll
    for (int j = 0; j < 4; ++j)
        aW1[j] = (_Float16)((g == 0) ? K2 * gW1[j * 64 + w * 16 + c] : 0.0f);

    // L2 A (16x16x32 x2): -2*K2*W2  (r-feed fold + exp2 pre-scale)
    f16x8 aW2[2];
#pragma unroll
    for (int kt = 0; kt < 2; ++kt)
#pragma unroll
        for (int j = 0; j < 8; ++j) {
            int k = kt * 32 + g * 8 + j;
            aW2[kt][j] = (_Float16)(-2.0f * K2 * gW2[k * 64 + w * 16 + c]);
        }

    // L3 A (16x16x32 x2): -2*W3, rows m=c (real c<3)
    f16x8 aW3[2];
#pragma unroll
    for (int kt = 0; kt < 2; ++kt)
#pragma unroll
        for (int j = 0; j < 8; ++j) {
            int k = kt * 32 + g * 8 + j;
            aW3[kt][j] = (_Float16)((c < 3) ? -2.0f * gW3[k * 3 + c] : 0.0f);
        }

    // C-frags (rows w*16+g*4+r): cb1 = K2*b1; cb2 = K2*(b2 + rowsum W2)
    f32x4 cb1, cb2;
#pragma unroll
    for (int r = 0; r < 4; ++r) {
        int row = w * 16 + g * 4 + r;
        cb1[r] = K2 * gb1[row];
        float rs = gb2[row];
        for (int k = 0; k < 64; ++k) rs += gW2[k * 64 + row];
        cb2[r] = K2 * rs;
    }

    // L3 consts: b3 + rowsum(W3) + greybox consts (+ per-step u term).
    const float xs0 = gxs[0], xs1 = gxs[1], xs2 = gxs[2];
    const float ig0 = 1.0f / (5.0f * xs0);
    const float ig1 = 1.0f / (5.0f * xs1);
    const float ig2 = 1.0f / (5.0f * xs2);
    const float ku  = gus[0] * ig0;
    float rs3[3];
#pragma unroll
    for (int m = 0; m < 3; ++m) {
        float s = gb3[m];
        for (int k = 0; k < 64; ++k) s += gW3[k * 3 + m];
        rs3[m] = s;
    }
    f32x4 cgb;
    cgb[0] = rs3[0] + (gum[0] - gxm[0]) * ig0;   // + u-term per step
    cgb[1] = rs3[1] - gxm[1] * ig1;
    cgb[2] = rs3[2] - gxm[2] * ig2;
    cgb[3] = 0.0f;
    const float cgb0_base = cgb[0];

    float x0v = gx0[batch * 3 + 0];
    float x1v = gx0[batch * 3 + 1];
    float x2v = gx0[batch * 3 + 2];

    auto feval = [&](float e0, float e1, float e2, float ue,
                     float& o0, float& o1, float& o2) {
        // Z B-frag (16x16x16): k=0..3 -> (x0,x1,x2,u) on g==0 lanes.
        unsigned z01 = 0u, z23 = 0u;
        if (g == 0) { z01 = pkrtz(e0, e1); z23 = pkrtz(e2, ue); }
        u32x2 zi = {z01, z23};
        f16x4 zb = __builtin_bit_cast(f16x4, zi);

        // L1: d1 = K2*(W1 z + b1); r1 = sigr(d1)
        f32x4 d1 = mfma16(aW1, zb, cb1);
        u32x2 hw = {pkrtz(sigr(d1[0]), sigr(d1[1])),
                    pkrtz(sigr(d1[2]), sigr(d1[3]))};
        *(u32x2*)&hb[0][c][w * 16 + g * 4] = hw;
        barrier_lds();
        f16x8 hA0 = *(const f16x8*)&hb[0][c][g * 8];
        f16x8 hA1 = *(const f16x8*)&hb[0][c][32 + g * 8];

        // L2: d2 = K2*(b2 + rowsumW2) + (-2*K2*W2) r1 ; r2 = sigr(d2)
        f32x4 d2 = __builtin_amdgcn_mfma_f32_16x16x32_f16(aW2[0], hA0, cb2, 0, 0, 0);
        d2 = __builtin_amdgcn_mfma_f32_16x16x32_f16(aW2[1], hA1, d2, 0, 0, 0);
        u32x2 qw = {pkrtz(sigr(d2[0]), sigr(d2[1])),
                    pkrtz(sigr(d2[2]), sigr(d2[3]))};
        *(u32x2*)&hb[1][c][w * 16 + g * 4] = qw;
        barrier_lds();
        f16x8 hB0 = *(const f16x8*)&hb[1][c][g * 8];
        f16x8 hB1 = *(const f16x8*)&hb[1][c][32 + g * 8];

        // L3: xdot rows (m = g*4+r, real m<3) = (-2*W3) r2 + consts
        f32x4 d3 = __builtin_amdgcn_mfma_f32_16x16x32_f16(aW3[0], hB0, cgb, 0, 0, 0);
        d3 = __builtin_amdgcn_mfma_f32_16x16x32_f16(aW3[1], hB1, d3, 0, 0, 0);

        // greybox residual: -e/TAU (xstd cancels exactly)
        o0 = __builtin_fmaf(-0.2f, e0, d3[0]);
        o1 = __builtin_fmaf(-0.2f, e1, d3[1]);
        o2 = __builtin_fmaf(-0.2f, e2, d3[2]);
    };

    float ucur = gu[batch * T];
    float* orow = gout + (size_t)batch * (3 * T);

    for (int t = 0; t < T; ++t) {
        if (w == 0 && g == 0) {          // ys[t] = pre-step state
            orow[t * 3 + 0] = x0v;
            orow[t * 3 + 1] = x1v;
            orow[t * 3 + 2] = x2v;
        }
        float unext = gu[batch * T + ((t + 1 < T) ? t + 1 : t)];

        cgb[0] = __builtin_fmaf(ucur, ku, cgb0_base);   // per-step u const

        float a0, a1, a2, b0, b1v, b2v, c0, c1, c2, d0, d1v, d2v;
        feval(x0v, x1v, x2v, ucur, a0, a1, a2);
        feval(x0v + 0.5f * a0, x1v + 0.5f * a1, x2v + 0.5f * a2, ucur, b0, b1v, b2v);
        feval(x0v + 0.5f * b0, x1v + 0.5f * b1v, x2v + 0.5f * b2v, ucur, c0, c1, c2);
        feval(x0v + c0, x1v + c1, x2v + c2, ucur, d0, d1v, d2v);

        x0v += (1.0f / 6.0f) * (a0 + 2.0f * b0 + 2.0f * c0 + d0);
        x1v += (1.0f / 6.0f) * (a1 + 2.0f * b1v + 2.0f * c1 + d1v);
        x2v += (1.0f / 6.0f) * (a2 + 2.0f * b2v + 2.0f * c2 + d2v);
        ucur = unext;
    }
}

extern "C" void kernel_launch(void* const* d_in, const int* in_sizes, int n_in,
                              void* d_out, int out_size, void* d_ws, size_t ws_size,
                              hipStream_t stream) {
    const float* u  = (const float*)d_in[0];
    const float* x0 = (const float*)d_in[1];
    const float* W1 = (const float*)d_in[2];
    const float* b1 = (const float*)d_in[3];
    const float* W2 = (const float*)d_in[4];
    const float* b2 = (const float*)d_in[5];
    const float* W3 = (const float*)d_in[6];
    const float* b3 = (const float*)d_in[7];
    const float* xm = (const float*)d_in[8];
    const float* xs = (const float*)d_in[9];
    const float* um = (const float*)d_in[10];
    const float* us = (const float*)d_in[11];
    // 8192 / 16 cols per block = 512 blocks x 256 threads (4 waves, H-split)
    rk4_kernel<<<512, 256, 0, stream>>>(u, x0, W1, b1, W2, b2, W3, b3,
                                        xm, xs, um, us, (float*)d_out);
}